// Round 9
// baseline (1058.209 us; speedup 1.0000x reference)
//
#include <hip/hip_runtime.h>
#include <hip/hip_fp16.h>
#include <cstdint>
#include <cstddef>

#define NN 100000
#define NE 1200000
#define NBKT 1563              // (NN+63)/64 buckets of 64 nodes
#define NB8  (8 * NBKT)        // per-(xcd,bucket) streams
#define CHK  4688              // (NE+255)/256 edges per partition/count8 block

typedef _Float16 f16x8 __attribute__((ext_vector_type(8)));
typedef float f32x4 __attribute__((ext_vector_type(4)));

// ================= degree (per node, XCD-affine ranges) =================
__global__ void count_xcd(const int* __restrict__ ei, int* __restrict__ cnt,
                          int E, int nPerRange) {
    int r = blockIdx.x & 7;
    int grp = blockIdx.x >> 3;
    int nGrp = gridDim.x >> 3;
    int lo = r * nPerRange, hi = lo + nPerRange;
    for (int e = grp * blockDim.x + threadIdx.x; e < E; e += nGrp * blockDim.x) {
        int d = ei[E + e];
        if (d >= lo && d < hi) atomicAdd(&cnt[d], 1);
    }
}

__global__ void dis_kernel(const int* __restrict__ cnt, float* __restrict__ dis, int n) {
    int i = blockIdx.x * blockDim.x + threadIdx.x;
    if (i < n) dis[i] = rsqrtf((float)cnt[i] + 1.0f);   // +1 self-loop
}

// ============ per-(r,bucket) histogram; slicing matches partition_k ============
__global__ void count8_k(const int* __restrict__ ei, int* __restrict__ cnt8, int E) {
    __shared__ int hist[NBKT];
    int tid = threadIdx.x;
    for (int i = tid; i < NBKT; i += 256) hist[i] = 0;
    __syncthreads();
    int r = blockIdx.x & 7;
    int lo = blockIdx.x * CHK, hi = min(lo + CHK, E);
    for (int e = lo + tid; e < hi; e += 256)
        atomicAdd(&hist[ei[E + e] >> 6], 1);
    __syncthreads();
    for (int i = tid; i < NBKT; i += 256)
        if (hist[i]) atomicAdd(&cnt8[r * NBKT + i], hist[i]);
}

// ---- 3-phase exclusive scan over cnt8 (m = NB8) -> base8, cur8 ----
__global__ void scan_phase1(const int* __restrict__ cnt, int* __restrict__ blkSum, int n) {
    __shared__ int red[256];
    int base = blockIdx.x * 1024, t = threadIdx.x;
    int s = 0;
#pragma unroll
    for (int j = 0; j < 4; j++) {
        int i = base + t * 4 + j;
        if (i < n) s += cnt[i];
    }
    red[t] = s;
    __syncthreads();
    for (int off = 128; off > 0; off >>= 1) {
        if (t < off) red[t] += red[t + off];
        __syncthreads();
    }
    if (t == 0) blkSum[blockIdx.x] = red[0];
}

__global__ void scan_phase2(int* __restrict__ blkSum, int* __restrict__ base, int nblk, int n) {
    __shared__ int sh[128];
    int t = threadIdx.x;
    int v = (t < nblk) ? blkSum[t] : 0;
    sh[t] = v;
    __syncthreads();
    for (int off = 1; off < 128; off <<= 1) {
        int u = (t >= off) ? sh[t - off] : 0;
        __syncthreads();
        sh[t] += u;
        __syncthreads();
    }
    if (t < nblk) blkSum[t] = (t == 0) ? 0 : sh[t - 1];
    if (t == 0) base[n] = sh[127];
}

__global__ void scan_phase3(const int* __restrict__ cnt, const int* __restrict__ blkSum,
                            int* __restrict__ base, int* __restrict__ cur, int n) {
    __shared__ int sh[256];
    int b0 = blockIdx.x * 1024, t = threadIdx.x;
    int idx = b0 + t * 4;
    int c[4];
    int s = 0;
#pragma unroll
    for (int j = 0; j < 4; j++) {
        int i = idx + j;
        c[j] = (i < n) ? cnt[i] : 0;
        s += c[j];
    }
    sh[t] = s;
    __syncthreads();
    for (int off = 1; off < 256; off <<= 1) {
        int u = (t >= off) ? sh[t - off] : 0;
        __syncthreads();
        sh[t] += u;
        __syncthreads();
    }
    int excl = blkSum[blockIdx.x] + ((t == 0) ? 0 : sh[t - 1]);
#pragma unroll
    for (int j = 0; j < 4; j++) {
        int i = idx + j;
        if (i < n) { base[i] = excl; cur[i] = excl; }
        excl += c[j];
    }
}

// ============ partition: append 4B records to per-(r,bucket) streams ============
// Stream (r,b) is written only by blocks with bid&7==r (one XCD under round-robin);
// positions are sequential per stream -> 64B lines fill inside that XCD's L2.
__global__ void partition_k(const int* __restrict__ ei, int* __restrict__ cur8,
                            unsigned* __restrict__ recs, int E) {
    int r = blockIdx.x & 7;
    int lo = blockIdx.x * CHK, hi = min(lo + CHK, E);
    for (int e = lo + threadIdx.x; e < hi; e += 256) {
        int d = ei[E + e];
        int s = ei[e];
        int b = d >> 6;
        int pos = atomicAdd(&cur8[r * NBKT + b], 1);
        recs[pos] = ((unsigned)s << 6) | (unsigned)(d & 63);
    }
}

// ============ bucket aggregation: fused gather + selfloop + bias + relu ============
// One block per bucket (64 nodes). LDS fp32 accumulator [64][65] (pad -> bank spread).
// 16 edge-groups x 16 lanes; per edge: 128B coalesced hw gather, 4 LDS float atomics.
__global__ __launch_bounds__(256) void agg_bucket(
    const int* __restrict__ base8, const int* __restrict__ cnt8,
    const unsigned* __restrict__ recs, const __half* __restrict__ hw,
    const float* __restrict__ dis, const float* __restrict__ bias,
    float* __restrict__ out, int n) {
    __shared__ float acc[64 * 65];
    __shared__ float disD[64];
    const int b = blockIdx.x, tid = threadIdx.x;
    for (int i = tid; i < 64 * 65; i += 256) acc[i] = 0.f;
    if (tid < 64) {
        int g = b * 64 + tid;
        disD[tid] = (g < n) ? dis[g] : 0.f;
    }
    __syncthreads();

    const uint2* hwq = (const uint2*)hw;   // row = 16 uint2 (64 fp16)
    const int grp = tid >> 4, sub = tid & 15;

    for (int r = 0; r < 8; ++r) {
        int sbase = base8[r * NBKT + b];
        int scnt  = cnt8[r * NBKT + b];
        for (int i = grp; i < scnt; i += 16) {
            unsigned key = recs[sbase + i];
            int src = key >> 6;
            int dl  = key & 63;
            float nrm = dis[src] * disD[dl];
            uint2 q = hwq[(size_t)src * 16 + sub];
            __half2 h01 = *(__half2*)&q.x;
            __half2 h23 = *(__half2*)&q.y;
            float2 f01 = __half22float2(h01);
            float2 f23 = __half22float2(h23);
            float* a = &acc[dl * 65 + sub * 4];
            atomicAdd(a + 0, f01.x * nrm);
            atomicAdd(a + 1, f01.y * nrm);
            atomicAdd(a + 2, f23.x * nrm);
            atomicAdd(a + 3, f23.y * nrm);
        }
    }
    __syncthreads();

    for (int slot = tid; slot < 64 * 16; slot += 256) {
        int node = slot >> 4, sb = slot & 15;
        int g = b * 64 + node;
        if (g < n) {
            float di = disD[node];
            float ds = di * di;
            uint2 qs = hwq[(size_t)g * 16 + sb];
            __half2 h01 = *(__half2*)&qs.x;
            __half2 h23 = *(__half2*)&qs.y;
            float2 f01 = __half22float2(h01);
            float2 f23 = __half22float2(h23);
            const float4 bb = ((const float4*)bias)[sb];
            float4 o;
            o.x = acc[node * 65 + sb * 4 + 0] + f01.x * ds + bb.x;
            o.y = acc[node * 65 + sb * 4 + 1] + f01.y * ds + bb.y;
            o.z = acc[node * 65 + sb * 4 + 2] + f23.x * ds + bb.z;
            o.w = acc[node * 65 + sb * 4 + 3] + f23.y * ds + bb.w;
            o.x = o.x > 0.f ? o.x : 0.f;
            o.y = o.y > 0.f ? o.y : 0.f;
            o.z = o.z > 0.f ? o.z : 0.f;
            o.w = o.w > 0.f ? o.w : 0.f;
            ((float4*)out)[(size_t)g * 16 + sb] = o;
        }
    }
}

// ============ MFMA GEMM: C[n,64] = A[n,K] @ W[K,64], fp16 in / fp32 acc / fp16 out ====
template <int K>
__global__ __launch_bounds__(256) void gemm_mfma(const float* __restrict__ A,
                                                 const float* __restrict__ W,
                                                 __half* __restrict__ C, int n) {
    constexpr int KB = K / 32;
    __shared__ f16x8 sAf[4 * KB * 64];   // [rt][kb][lane]
    __shared__ f16x8 sWf[4 * KB * 64];   // [ct][kb][lane]
    const int tid = threadIdx.x;
    const int row0 = blockIdx.x * 64;

    _Float16* sAh = (_Float16*)sAf;
    const float4* A4 = (const float4*)A;
#pragma unroll
    for (int it = 0; it < K / 16; ++it) {
        int f = it * 256 + tid;
        int row = f / (K / 4);
        int kq = f % (K / 4);
        int k0 = kq * 4;
        float4 a;
        if (row0 + row < n) a = A4[(size_t)(row0 + row) * (K / 4) + kq];
        else { a.x = 0.f; a.y = 0.f; a.z = 0.f; a.w = 0.f; }
        int rt = row >> 4;
        int kb = k0 >> 5;
        int lane = (row & 15) | (((k0 >> 3) & 3) << 4);
        int base = ((rt * KB + kb) * 64 + lane) * 8 + (k0 & 7);
        sAh[base + 0] = (_Float16)a.x;
        sAh[base + 1] = (_Float16)a.y;
        sAh[base + 2] = (_Float16)a.z;
        sAh[base + 3] = (_Float16)a.w;
    }
    _Float16* sWh = (_Float16*)sWf;
    {
        int nn = tid & 63;
        int ct = nn >> 4;
        int lbase = nn & 15;
        for (int k = tid >> 6; k < K; k += 4) {
            float w = W[(size_t)k * 64 + nn];
            int kb = k >> 5;
            int lane = lbase | (((k >> 3) & 3) << 4);
            sWh[((ct * KB + kb) * 64 + lane) * 8 + (k & 7)] = (_Float16)w;
        }
    }
    __syncthreads();

    const int wv = tid >> 6;
    const int lane = tid & 63;
    f32x4 acc[4];
#pragma unroll
    for (int rt = 0; rt < 4; ++rt) acc[rt] = (f32x4){0.f, 0.f, 0.f, 0.f};

#pragma unroll
    for (int kb = 0; kb < KB; ++kb) {
        f16x8 bf = sWf[(wv * KB + kb) * 64 + lane];
#pragma unroll
        for (int rt = 0; rt < 4; ++rt) {
            f16x8 af = sAf[(rt * KB + kb) * 64 + lane];
            acc[rt] = __builtin_amdgcn_mfma_f32_16x16x32_f16(af, bf, acc[rt], 0, 0, 0);
        }
    }

    int col = wv * 16 + (lane & 15);
    int rbase = (lane >> 4) * 4;
#pragma unroll
    for (int rt = 0; rt < 4; ++rt) {
#pragma unroll
        for (int r = 0; r < 4; ++r) {
            int row = row0 + rt * 16 + rbase + r;
            if (row < n) C[(size_t)row * 64 + col] = __float2half(acc[rt][r]);
        }
    }
}

// ================= fallback (atomic path, small ws) =================
__global__ void fill_kernel(float* __restrict__ p, float v, int n) {
    int i = blockIdx.x * blockDim.x + threadIdx.x;
    if (i < n) p[i] = v;
}
__global__ void degree_kernel(const int* __restrict__ ei, float* __restrict__ deg, int E) {
    int stride = gridDim.x * blockDim.x;
    for (int e = blockIdx.x * blockDim.x + threadIdx.x; e < E; e += stride)
        atomicAdd(&deg[ei[E + e]], 1.0f);
}
__global__ void rsqrt_kernel(float* __restrict__ deg, int n) {
    int i = blockIdx.x * blockDim.x + threadIdx.x;
    if (i < n) deg[i] = rsqrtf(deg[i]);
}
template <int K>
__global__ __launch_bounds__(256) void gemm_tile(const float* __restrict__ A,
                                                 const float* __restrict__ W,
                                                 float* __restrict__ C, int n) {
    __shared__ float sA[64 * K];
    __shared__ float sW[K * 64];
    const int tid = threadIdx.x;
    const int row0 = blockIdx.x * 64;
    const int rows = min(64, n - row0);
    const float4* W4 = (const float4*)W;
    float4* sW4 = (float4*)sW;
    for (int i = tid; i < K * 16; i += 256) sW4[i] = W4[i];
    const float4* A4 = (const float4*)(A + (size_t)row0 * K);
    float4* sA4 = (float4*)sA;
    const int nElem = rows * (K / 4);
    for (int i = tid; i < nElem; i += 256) sA4[i] = A4[i];
    __syncthreads();
    const int col = tid & 63;
    const int ty  = tid >> 6;
    float acc[16];
#pragma unroll
    for (int r = 0; r < 16; r++) acc[r] = 0.f;
    for (int k = 0; k < K; k += 4) {
        float w0 = sW[(k + 0) * 64 + col];
        float w1 = sW[(k + 1) * 64 + col];
        float w2 = sW[(k + 2) * 64 + col];
        float w3 = sW[(k + 3) * 64 + col];
#pragma unroll
        for (int r = 0; r < 16; r++) {
            const float4 a = *(const float4*)&sA[(ty + 4 * r) * K + k];
            acc[r] = fmaf(a.x, w0, acc[r]);
            acc[r] = fmaf(a.y, w1, acc[r]);
            acc[r] = fmaf(a.z, w2, acc[r]);
            acc[r] = fmaf(a.w, w3, acc[r]);
        }
    }
#pragma unroll
    for (int r = 0; r < 16; r++) {
        int row = ty + 4 * r;
        if (row < rows) C[(size_t)(row0 + row) * 64 + col] = acc[r];
    }
}
__global__ void scatter_kernel(const int* __restrict__ ei, const float* __restrict__ hw,
                               const float* __restrict__ dis, float* __restrict__ agg, int E) {
    int gtid = blockIdx.x * blockDim.x + threadIdx.x;
    int wave = gtid >> 6, lane = threadIdx.x & 63;
    int nwaves = (gridDim.x * blockDim.x) >> 6;
    for (int e = wave; e < E; e += nwaves) {
        int s = ei[e], d = ei[E + e];
        float v = hw[(size_t)s * 64 + lane] * dis[s] * dis[d];
        atomicAdd(&agg[(size_t)d * 64 + lane], v);
    }
}
__global__ void finalize_kernel(float* __restrict__ agg, const float* __restrict__ hw,
                                const float* __restrict__ dis, const float* __restrict__ b, int n) {
    int i = blockIdx.x * blockDim.x + threadIdx.x;
    if (i < n * 64) {
        int node = i >> 6, col = i & 63;
        float di = dis[node];
        float v = agg[i] + hw[i] * di * di + b[col];
        agg[i] = v > 0.0f ? v : 0.0f;
    }
}

extern "C" void kernel_launch(void* const* d_in, const int* in_sizes, int n_in,
                              void* d_out, int out_size, void* d_ws, size_t ws_size,
                              hipStream_t stream) {
    const float* x  = (const float*)d_in[0];
    const int*   ei = (const int*)d_in[1];   // int32 [2, E] flat
    const float* W1 = (const float*)d_in[2];
    const float* b1 = (const float*)d_in[3];
    const float* W2 = (const float*)d_in[4];
    const float* b2 = (const float*)d_in[5];
    float* out = (float*)d_out;

    const int N = NN, E = NE;
    char* ws = (char*)d_ws;
    const int gemmGrid = (N + 63) / 64;
    const int nPerRange = (N + 7) / 8;   // 12500

    if (ws_size >= 38200000u) {
        // ---- bucketed pipeline ----
        int*      cnt    = (int*)ws;                        // 0 .. 512K (N ints)
        float*    dis    = (float*)(ws + (1u << 19));       // 512K .. 1M
        int*      cnt8   = (int*)(ws + (1u << 20));         // 1M + 0   (NB8 ints, 50KB)
        int*      base8  = (int*)(ws + (1u << 20) + (1u << 16));  // +64K (NB8+1)
        int*      cur8   = (int*)(ws + (1u << 20) + (2u << 16));  // +128K
        int*      blkSum = (int*)(ws + (1u << 20) + (3u << 16));  // +192K (13 ints)
        unsigned* recs   = (unsigned*)(ws + (2u << 20));    // 2M .. 6.8M (4.8MB)
        __half*   hwa    = (__half*)(ws + (8u << 20));      // 8M .. 20.8M (12.8MB fp16)

        const int nblk8 = (NB8 + 1023) / 1024;   // 13

        hipMemsetAsync(cnt, 0, N * sizeof(int), stream);
        hipMemsetAsync(cnt8, 0, NB8 * sizeof(int), stream);
        count_xcd<<<2048, 256, 0, stream>>>(ei, cnt, E, nPerRange);
        dis_kernel<<<(N + 255) / 256, 256, 0, stream>>>(cnt, dis, N);
        count8_k<<<256, 256, 0, stream>>>(ei, cnt8, E);
        scan_phase1<<<nblk8, 256, 0, stream>>>(cnt8, blkSum, NB8);
        scan_phase2<<<1, 128, 0, stream>>>(blkSum, base8, nblk8, NB8);
        scan_phase3<<<nblk8, 256, 0, stream>>>(cnt8, blkSum, base8, cur8, NB8);
        partition_k<<<256, 256, 0, stream>>>(ei, cur8, recs, E);

        // layer 1: hw1(fp16) -> hwa; h -> out
        gemm_mfma<128><<<gemmGrid, 256, 0, stream>>>(x, W1, hwa, N);
        agg_bucket<<<NBKT, 256, 0, stream>>>(base8, cnt8, recs, hwa, dis, b1, out, N);
        // layer 2: hw2(fp16) -> hwa; out final
        gemm_mfma<64><<<gemmGrid, 256, 0, stream>>>(out, W2, hwa, N);
        agg_bucket<<<NBKT, 256, 0, stream>>>(base8, cnt8, recs, hwa, dis, b2, out, N);
    } else {
        // ---- fallback: atomic path (fp32 throughout) ----
        float* dis  = (float*)ws;
        float* bufA = (float*)(ws + (1 << 19));
        const size_t featBytes = (size_t)N * 64 * sizeof(float);

        fill_kernel<<<(N + 255) / 256, 256, 0, stream>>>(dis, 1.0f, N);
        degree_kernel<<<2048, 256, 0, stream>>>(ei, dis, E);
        rsqrt_kernel<<<(N + 255) / 256, 256, 0, stream>>>(dis, N);

        gemm_tile<128><<<gemmGrid, 256, 0, stream>>>(x, W1, bufA, N);
        hipMemsetAsync(out, 0, featBytes, stream);
        scatter_kernel<<<2048, 256, 0, stream>>>(ei, bufA, dis, out, E);
        finalize_kernel<<<(N * 64 + 255) / 256, 256, 0, stream>>>(out, bufA, dis, b1, N);

        gemm_tile<64><<<gemmGrid, 256, 0, stream>>>(out, W2, bufA, N);
        hipMemsetAsync(out, 0, featBytes, stream);
        scatter_kernel<<<2048, 256, 0, stream>>>(ei, bufA, dis, out, E);
        finalize_kernel<<<(N * 64 + 255) / 256, 256, 0, stream>>>(out, bufA, dis, b2, N);
    }
}

// Round 10
// 210.554 us; speedup vs baseline: 5.0258x; 5.0258x over previous
//
#include <hip/hip_runtime.h>
#include <hip/hip_fp16.h>
#include <cstdint>
#include <cstddef>

#define NN 100000
#define NE 1200000
#define NBKT 1563              // (NN+63)/64 buckets of 64 dst nodes
#define NB8  (8 * NBKT)        // per-(xcd,bucket) streams
#define CAP  256               // slab capacity per stream (mean 96, sigma ~10)
#define CHK2 586               // (NE+2047)/2048 edges per partition block

typedef _Float16 f16x8 __attribute__((ext_vector_type(8)));
typedef float f32x4 __attribute__((ext_vector_type(4)));

// ================= degree + norm =================
__global__ void count_plain(const int* __restrict__ ei, int* __restrict__ cnt, int E) {
    int stride = gridDim.x * blockDim.x;
    for (int e = blockIdx.x * blockDim.x + threadIdx.x; e < E; e += stride)
        atomicAdd(&cnt[ei[E + e]], 1);
}

__global__ void dis_kernel(const int* __restrict__ cnt, float* __restrict__ dis, int n) {
    int i = blockIdx.x * blockDim.x + threadIdx.x;
    if (i < n) dis[i] = rsqrtf((float)cnt[i] + 1.0f);   // +1 self-loop
}

// ============ partition: append 4B src-records to per-(r,bucket) slabs ============
// Slab (r,b) written only by blocks with bid&7==r; positions sequential per slab.
__global__ void partition_k(const int* __restrict__ ei, int* __restrict__ cur8,
                            unsigned* __restrict__ recs, unsigned* __restrict__ ovfn,
                            uint2* __restrict__ ovf, int E) {
    int r = blockIdx.x & 7;
    int lo = blockIdx.x * CHK2, hi = min(lo + CHK2, E);
    for (int e = lo + threadIdx.x; e < hi; e += 256) {
        int d = ei[E + e];
        int s = ei[e];
        int idx = r * NBKT + (d >> 6);
        int pos = atomicAdd(&cur8[idx], 1);
        if (pos < CAP) recs[(size_t)idx * CAP + pos] = ((unsigned)s << 6) | (unsigned)(d & 63);
        else {  // astronomically unlikely (16 sigma); keep exact anyway
            unsigned o = atomicAdd(ovfn, 1);
            if (o < 4096) ovf[o] = make_uint2((unsigned)s, (unsigned)d);
        }
    }
}

// ============ bucket aggregation: LDS counting-sort + register accumulation ============
// One block per bucket (64 dst nodes). Sort 8 streams' records by dst-low in LDS,
// then slot (16 lanes) accumulates 4 nodes: 4-deep batched 128B gathers of hwa rows.
// hwa rows already carry dis[src]; output applies dis[dst], bias, relu.
__global__ __launch_bounds__(256) void agg_bucket2(
    const int* __restrict__ cur8, const unsigned* __restrict__ recs,
    const __half* __restrict__ hw, const float* __restrict__ dis,
    const float* __restrict__ bias, float* __restrict__ out,
    const unsigned* __restrict__ ovfn, const uint2* __restrict__ ovf, int n) {
    __shared__ unsigned srec[8 * CAP];
    __shared__ int cnt[64], off[65], woff[64], pfx[64];
    __shared__ float disD[64];
    const int b = blockIdx.x, tid = threadIdx.x;
    if (tid < 64) {
        cnt[tid] = 0;
        int g = b * 64 + tid;
        disD[tid] = (g < n) ? dis[g] : 0.f;
    }
    __syncthreads();

    int c[8];
#pragma unroll
    for (int r = 0; r < 8; r++) c[r] = min(cur8[r * NBKT + b], CAP);

    // count pass
#pragma unroll
    for (int r = 0; r < 8; r++) {
        const unsigned* st = recs + (size_t)(r * NBKT + b) * CAP;
        for (int i = tid; i < c[r]; i += 256) atomicAdd(&cnt[st[i] & 63], 1);
    }
    __syncthreads();
    // inclusive prefix over 64 -> off (exclusive bounds), woff (scatter cursors)
    if (tid < 64) pfx[tid] = cnt[tid];
    __syncthreads();
    for (int s = 1; s < 64; s <<= 1) {
        int v = (tid < 64 && tid >= s) ? pfx[tid - s] : 0;
        __syncthreads();
        if (tid < 64) pfx[tid] += v;
        __syncthreads();
    }
    if (tid == 0) off[0] = 0;
    if (tid < 64) { off[tid + 1] = pfx[tid]; woff[tid] = pfx[tid] - cnt[tid]; }
    __syncthreads();
    // scatter pass
#pragma unroll
    for (int r = 0; r < 8; r++) {
        const unsigned* st = recs + (size_t)(r * NBKT + b) * CAP;
        for (int i = tid; i < c[r]; i += 256) {
            unsigned k = st[i];
            int p = atomicAdd(&woff[k & 63], 1);
            srec[p] = k;
        }
    }
    __syncthreads();

    // accumulate: slot = tid>>4 handles nodes slot*4+j, 16 lanes = 16 feature-quads
    const uint2* hwq = (const uint2*)hw;   // row = 16 uint2 (64 fp16)
    const int slot = tid >> 4, sub = tid & 15;
    const unsigned no = *ovfn;
    const float4 bb = ((const float4*)bias)[sub];

    for (int j = 0; j < 4; j++) {
        int nl = slot * 4 + j;
        int g = b * 64 + nl;
        if (g >= n) break;
        uint2 qs = hwq[(size_t)g * 16 + sub];   // self row
        float2 f01 = __half22float2(*(__half2*)&qs.x);
        float2 f23 = __half22float2(*(__half2*)&qs.y);
        float a0 = f01.x, a1 = f01.y, a2 = f23.x, a3 = f23.y;

        int e = off[nl], end = off[nl + 1];
        for (; e + 4 <= end; e += 4) {
            int s0 = srec[e + 0] >> 6;
            int s1 = srec[e + 1] >> 6;
            int s2 = srec[e + 2] >> 6;
            int s3 = srec[e + 3] >> 6;
            uint2 q0 = hwq[(size_t)s0 * 16 + sub];
            uint2 q1 = hwq[(size_t)s1 * 16 + sub];
            uint2 q2 = hwq[(size_t)s2 * 16 + sub];
            uint2 q3 = hwq[(size_t)s3 * 16 + sub];
            float2 g01, g23;
            g01 = __half22float2(*(__half2*)&q0.x); g23 = __half22float2(*(__half2*)&q0.y);
            a0 += g01.x; a1 += g01.y; a2 += g23.x; a3 += g23.y;
            g01 = __half22float2(*(__half2*)&q1.x); g23 = __half22float2(*(__half2*)&q1.y);
            a0 += g01.x; a1 += g01.y; a2 += g23.x; a3 += g23.y;
            g01 = __half22float2(*(__half2*)&q2.x); g23 = __half22float2(*(__half2*)&q2.y);
            a0 += g01.x; a1 += g01.y; a2 += g23.x; a3 += g23.y;
            g01 = __half22float2(*(__half2*)&q3.x); g23 = __half22float2(*(__half2*)&q3.y);
            a0 += g01.x; a1 += g01.y; a2 += g23.x; a3 += g23.y;
        }
        for (; e < end; e++) {
            uint2 q = hwq[(size_t)(srec[e] >> 6) * 16 + sub];
            float2 g01 = __half22float2(*(__half2*)&q.x);
            float2 g23 = __half22float2(*(__half2*)&q.y);
            a0 += g01.x; a1 += g01.y; a2 += g23.x; a3 += g23.y;
        }
        for (unsigned i = 0; i < no; i++) {   // overflow records (normally none)
            uint2 o = ovf[i];
            if ((int)o.y == g) {
                uint2 q = hwq[(size_t)o.x * 16 + sub];
                float2 g01 = __half22float2(*(__half2*)&q.x);
                float2 g23 = __half22float2(*(__half2*)&q.y);
                a0 += g01.x; a1 += g01.y; a2 += g23.x; a3 += g23.y;
            }
        }
        float di = disD[nl];
        float4 oo;
        oo.x = fmaf(di, a0, bb.x);
        oo.y = fmaf(di, a1, bb.y);
        oo.z = fmaf(di, a2, bb.z);
        oo.w = fmaf(di, a3, bb.w);
        oo.x = oo.x > 0.f ? oo.x : 0.f;
        oo.y = oo.y > 0.f ? oo.y : 0.f;
        oo.z = oo.z > 0.f ? oo.z : 0.f;
        oo.w = oo.w > 0.f ? oo.w : 0.f;
        ((float4*)out)[(size_t)g * 16 + sub] = oo;
    }
}

// ============ MFMA GEMM: C[n,64] = (A[n,K] @ W[K,64]) * dis[row], fp16 out ============
template <int K>
__global__ __launch_bounds__(256) void gemm_mfma(const float* __restrict__ A,
                                                 const float* __restrict__ W,
                                                 const float* __restrict__ dis,
                                                 __half* __restrict__ C, int n) {
    constexpr int KB = K / 32;
    __shared__ f16x8 sAf[4 * KB * 64];   // [rt][kb][lane]
    __shared__ f16x8 sWf[4 * KB * 64];   // [ct][kb][lane]
    __shared__ float sdis[64];
    const int tid = threadIdx.x;
    const int row0 = blockIdx.x * 64;

    if (tid < 64) {
        int rw = row0 + tid;
        sdis[tid] = (rw < n) ? dis[rw] : 0.f;
    }

    _Float16* sAh = (_Float16*)sAf;
    const float4* A4 = (const float4*)A;
#pragma unroll
    for (int it = 0; it < K / 16; ++it) {
        int f = it * 256 + tid;
        int row = f / (K / 4);
        int kq = f % (K / 4);
        int k0 = kq * 4;
        float4 a;
        if (row0 + row < n) a = A4[(size_t)(row0 + row) * (K / 4) + kq];
        else { a.x = 0.f; a.y = 0.f; a.z = 0.f; a.w = 0.f; }
        int rt = row >> 4;
        int kb = k0 >> 5;
        int lane = (row & 15) | (((k0 >> 3) & 3) << 4);
        int base = ((rt * KB + kb) * 64 + lane) * 8 + (k0 & 7);
        sAh[base + 0] = (_Float16)a.x;
        sAh[base + 1] = (_Float16)a.y;
        sAh[base + 2] = (_Float16)a.z;
        sAh[base + 3] = (_Float16)a.w;
    }
    _Float16* sWh = (_Float16*)sWf;
    {
        int nn = tid & 63;
        int ct = nn >> 4;
        int lbase = nn & 15;
        for (int k = tid >> 6; k < K; k += 4) {
            float w = W[(size_t)k * 64 + nn];
            int kb = k >> 5;
            int lane = lbase | (((k >> 3) & 3) << 4);
            sWh[((ct * KB + kb) * 64 + lane) * 8 + (k & 7)] = (_Float16)w;
        }
    }
    __syncthreads();

    const int wv = tid >> 6;
    const int lane = tid & 63;
    f32x4 acc[4];
#pragma unroll
    for (int rt = 0; rt < 4; ++rt) acc[rt] = (f32x4){0.f, 0.f, 0.f, 0.f};

#pragma unroll
    for (int kb = 0; kb < KB; ++kb) {
        f16x8 bf = sWf[(wv * KB + kb) * 64 + lane];
#pragma unroll
        for (int rt = 0; rt < 4; ++rt) {
            f16x8 af = sAf[(rt * KB + kb) * 64 + lane];
            acc[rt] = __builtin_amdgcn_mfma_f32_16x16x32_f16(af, bf, acc[rt], 0, 0, 0);
        }
    }

    int col = wv * 16 + (lane & 15);
    int rbase = (lane >> 4) * 4;
#pragma unroll
    for (int rt = 0; rt < 4; ++rt) {
#pragma unroll
        for (int r = 0; r < 4; ++r) {
            int row = row0 + rt * 16 + rbase + r;
            if (row < n)
                C[(size_t)row * 64 + col] = __float2half(acc[rt][r] * sdis[rt * 16 + rbase + r]);
        }
    }
}

// ================= fallback (atomic path, small ws) =================
__global__ void fill_kernel(float* __restrict__ p, float v, int n) {
    int i = blockIdx.x * blockDim.x + threadIdx.x;
    if (i < n) p[i] = v;
}
__global__ void degree_kernel(const int* __restrict__ ei, float* __restrict__ deg, int E) {
    int stride = gridDim.x * blockDim.x;
    for (int e = blockIdx.x * blockDim.x + threadIdx.x; e < E; e += stride)
        atomicAdd(&deg[ei[E + e]], 1.0f);
}
__global__ void rsqrt_kernel(float* __restrict__ deg, int n) {
    int i = blockIdx.x * blockDim.x + threadIdx.x;
    if (i < n) deg[i] = rsqrtf(deg[i]);
}
template <int K>
__global__ __launch_bounds__(256) void gemm_tile(const float* __restrict__ A,
                                                 const float* __restrict__ W,
                                                 float* __restrict__ C, int n) {
    __shared__ float sA[64 * K];
    __shared__ float sW[K * 64];
    const int tid = threadIdx.x;
    const int row0 = blockIdx.x * 64;
    const int rows = min(64, n - row0);
    const float4* W4 = (const float4*)W;
    float4* sW4 = (float4*)sW;
    for (int i = tid; i < K * 16; i += 256) sW4[i] = W4[i];
    const float4* A4 = (const float4*)(A + (size_t)row0 * K);
    float4* sA4 = (float4*)sA;
    const int nElem = rows * (K / 4);
    for (int i = tid; i < nElem; i += 256) sA4[i] = A4[i];
    __syncthreads();
    const int col = tid & 63;
    const int ty  = tid >> 6;
    float acc[16];
#pragma unroll
    for (int r = 0; r < 16; r++) acc[r] = 0.f;
    for (int k = 0; k < K; k += 4) {
        float w0 = sW[(k + 0) * 64 + col];
        float w1 = sW[(k + 1) * 64 + col];
        float w2 = sW[(k + 2) * 64 + col];
        float w3 = sW[(k + 3) * 64 + col];
#pragma unroll
        for (int r = 0; r < 16; r++) {
            const float4 a = *(const float4*)&sA[(ty + 4 * r) * K + k];
            acc[r] = fmaf(a.x, w0, acc[r]);
            acc[r] = fmaf(a.y, w1, acc[r]);
            acc[r] = fmaf(a.z, w2, acc[r]);
            acc[r] = fmaf(a.w, w3, acc[r]);
        }
    }
#pragma unroll
    for (int r = 0; r < 16; r++) {
        int row = ty + 4 * r;
        if (row < rows) C[(size_t)(row0 + row) * 64 + col] = acc[r];
    }
}
__global__ void scatter_kernel(const int* __restrict__ ei, const float* __restrict__ hw,
                               const float* __restrict__ dis, float* __restrict__ agg, int E) {
    int gtid = blockIdx.x * blockDim.x + threadIdx.x;
    int wave = gtid >> 6, lane = threadIdx.x & 63;
    int nwaves = (gridDim.x * blockDim.x) >> 6;
    for (int e = wave; e < E; e += nwaves) {
        int s = ei[e], d = ei[E + e];
        float v = hw[(size_t)s * 64 + lane] * dis[s] * dis[d];
        atomicAdd(&agg[(size_t)d * 64 + lane], v);
    }
}
__global__ void finalize_kernel(float* __restrict__ agg, const float* __restrict__ hw,
                                const float* __restrict__ dis, const float* __restrict__ b, int n) {
    int i = blockIdx.x * blockDim.x + threadIdx.x;
    if (i < n * 64) {
        int node = i >> 6, col = i & 63;
        float di = dis[node];
        float v = agg[i] + hw[i] * di * di + b[col];
        agg[i] = v > 0.0f ? v : 0.0f;
    }
}

extern "C" void kernel_launch(void* const* d_in, const int* in_sizes, int n_in,
                              void* d_out, int out_size, void* d_ws, size_t ws_size,
                              hipStream_t stream) {
    const float* x  = (const float*)d_in[0];
    const int*   ei = (const int*)d_in[1];   // int32 [2, E] flat
    const float* W1 = (const float*)d_in[2];
    const float* b1 = (const float*)d_in[3];
    const float* W2 = (const float*)d_in[4];
    const float* b2 = (const float*)d_in[5];
    float* out = (float*)d_out;

    const int N = NN, E = NE;
    char* ws = (char*)d_ws;
    const int gemmGrid = (N + 63) / 64;

    if (ws_size >= 38200000u) {
        // ---- factorized-norm bucketed pipeline ----
        int*      cnt  = (int*)ws;                         // 0 .. 400K (pad 512K)
        float*    dis  = (float*)(ws + (1u << 19));        // 512K .. 912K (pad 1M)
        int*      cur8 = (int*)(ws + (1u << 20));          // 1M .. +50KB (pad 1.25M)
        unsigned* ovfn = (unsigned*)(ws + 1310720u);       // 1.25M (4B)
        uint2*    ovf  = (uint2*)(ws + 1314816u);          // 1.25M+4K .. +32KB
        unsigned* recs = (unsigned*)(ws + (2u << 20));     // 2M .. 14.3M (NB8*CAP*4)
        __half*   hwa  = (__half*)(ws + 15728640u);        // 15M .. 27.8M (fp16)

        hipMemsetAsync(cnt, 0, N * sizeof(int), stream);
        hipMemsetAsync(cur8, 0, NB8 * sizeof(int), stream);
        hipMemsetAsync(ovfn, 0, sizeof(unsigned), stream);
        count_plain<<<1024, 256, 0, stream>>>(ei, cnt, E);
        dis_kernel<<<(N + 255) / 256, 256, 0, stream>>>(cnt, dis, N);
        partition_k<<<2048, 256, 0, stream>>>(ei, cur8, recs, ovfn, ovf, E);

        // layer 1: hw1(fp16, *dis) -> hwa; h -> out
        gemm_mfma<128><<<gemmGrid, 256, 0, stream>>>(x, W1, dis, hwa, N);
        agg_bucket2<<<NBKT, 256, 0, stream>>>(cur8, recs, hwa, dis, b1, out, ovfn, ovf, N);
        // layer 2
        gemm_mfma<64><<<gemmGrid, 256, 0, stream>>>(out, W2, dis, hwa, N);
        agg_bucket2<<<NBKT, 256, 0, stream>>>(cur8, recs, hwa, dis, b2, out, ovfn, ovf, N);
    } else {
        // ---- fallback: atomic path (fp32 throughout) ----
        float* dis  = (float*)ws;
        float* bufA = (float*)(ws + (1 << 19));
        const size_t featBytes = (size_t)N * 64 * sizeof(float);

        fill_kernel<<<(N + 255) / 256, 256, 0, stream>>>(dis, 1.0f, N);
        degree_kernel<<<2048, 256, 0, stream>>>(ei, dis, E);
        rsqrt_kernel<<<(N + 255) / 256, 256, 0, stream>>>(dis, N);

        gemm_tile<128><<<gemmGrid, 256, 0, stream>>>(x, W1, bufA, N);
        hipMemsetAsync(out, 0, featBytes, stream);
        scatter_kernel<<<2048, 256, 0, stream>>>(ei, bufA, dis, out, E);
        finalize_kernel<<<(N * 64 + 255) / 256, 256, 0, stream>>>(out, bufA, dis, b1, N);

        gemm_tile<64><<<gemmGrid, 256, 0, stream>>>(out, W2, bufA, N);
        hipMemsetAsync(out, 0, featBytes, stream);
        scatter_kernel<<<2048, 256, 0, stream>>>(ei, bufA, dis, out, E);
        finalize_kernel<<<(N * 64 + 255) / 256, 256, 0, stream>>>(out, bufA, dis, b2, N);
    }
}

// Round 11
// 129.548 us; speedup vs baseline: 8.1685x; 1.6253x over previous
//
#include <hip/hip_runtime.h>
#include <hip/hip_fp16.h>
#include <cstdint>
#include <cstddef>

#define NN 100000
#define NE 1200000
#define NBKT 1563              // (NN+63)/64 buckets of 64 dst nodes
#define CAP_B 2048             // slab capacity per bucket (mean 768)
#define PBLK 256               // partition blocks
#define PCHK ((NE + PBLK - 1) / PBLK)   // 4688 edges per partition block

typedef _Float16 f16x8 __attribute__((ext_vector_type(8)));
typedef float f32x4 __attribute__((ext_vector_type(4)));

// ============ partition: hierarchical reservation, per-bucket slabs ============
// Phase A: LDS histogram of this block's chunk. Phase B: one global atomicAdd per
// nonzero bucket reserves a contiguous range. Phase C: re-read chunk (L2-hot),
// LDS cursor assigns local pos, write 4B src-record.
__global__ __launch_bounds__(256) void partition_hier(
    const int* __restrict__ ei, int* __restrict__ cur,
    unsigned* __restrict__ recs, unsigned* __restrict__ ovfn,
    uint2* __restrict__ ovf, int E) {
    __shared__ int hist[NBKT];
    __shared__ int base[NBKT];
    const int tid = threadIdx.x;
    for (int i = tid; i < NBKT; i += 256) hist[i] = 0;
    __syncthreads();
    const int lo = blockIdx.x * PCHK, hi = min(lo + PCHK, E);
    for (int e = lo + tid; e < hi; e += 256)
        atomicAdd(&hist[ei[E + e] >> 6], 1);
    __syncthreads();
    for (int i = tid; i < NBKT; i += 256) {
        int c = hist[i];
        base[i] = c ? atomicAdd(&cur[i], c) : 0;
        hist[i] = 0;   // reuse as local cursor
    }
    __syncthreads();
    for (int e = lo + tid; e < hi; e += 256) {
        int d = ei[E + e];
        int s = ei[e];
        int b = d >> 6;
        int lp = atomicAdd(&hist[b], 1);
        int pos = base[b] + lp;
        if (pos < CAP_B)
            recs[(size_t)b * CAP_B + pos] = ((unsigned)s << 6) | (unsigned)(d & 63);
        else {   // ~20 sigma out; keep exact anyway
            unsigned o = atomicAdd(ovfn, 1);
            if (o < 4096) ovf[o] = make_uint2((unsigned)s, (unsigned)d);
        }
    }
}

// ============ per-node degree -> dis, from partitioned streams ============
__global__ __launch_bounds__(256) void bucket_dis(
    const int* __restrict__ cur, const unsigned* __restrict__ recs,
    const unsigned* __restrict__ ovfn, const uint2* __restrict__ ovf,
    float* __restrict__ dis, int n) {
    __shared__ int cnt[64];
    const int b = blockIdx.x, tid = threadIdx.x;
    if (tid < 64) cnt[tid] = 0;
    __syncthreads();
    int c = min(cur[b], CAP_B);
    const unsigned* st = recs + (size_t)b * CAP_B;
    for (int i = tid; i < c; i += 256) atomicAdd(&cnt[st[i] & 63], 1);
    __syncthreads();
    if (tid < 64) {
        int g = b * 64 + tid;
        if (g < n) {
            int cc = cnt[tid];
            unsigned no = *ovfn;
            for (unsigned i = 0; i < no; i++)
                if ((int)ovf[i].y == g) cc++;
            dis[g] = rsqrtf((float)cc + 1.0f);   // +1 self-loop
        }
    }
}

// ============ bucket aggregation: LDS counting-sort + 8-deep register gather ============
// hwa rows already carry dis[src]; output applies dis[dst], bias, relu.
__global__ __launch_bounds__(256) void agg_bucket3(
    const int* __restrict__ cur, const unsigned* __restrict__ recs,
    const __half* __restrict__ hw, const float* __restrict__ dis,
    const float* __restrict__ bias, float* __restrict__ out,
    const unsigned* __restrict__ ovfn, const uint2* __restrict__ ovf, int n) {
    __shared__ unsigned srec[CAP_B];
    __shared__ int cnt[64], off[65], woff[64], pfx[64];
    __shared__ float disD[64];
    const int b = blockIdx.x, tid = threadIdx.x;
    if (tid < 64) {
        cnt[tid] = 0;
        int g = b * 64 + tid;
        disD[tid] = (g < n) ? dis[g] : 0.f;
    }
    __syncthreads();

    const int c = min(cur[b], CAP_B);
    const unsigned* st = recs + (size_t)b * CAP_B;
    for (int i = tid; i < c; i += 256) atomicAdd(&cnt[st[i] & 63], 1);
    __syncthreads();
    if (tid < 64) pfx[tid] = cnt[tid];
    __syncthreads();
    for (int s = 1; s < 64; s <<= 1) {
        int v = (tid < 64 && tid >= s) ? pfx[tid - s] : 0;
        __syncthreads();
        if (tid < 64) pfx[tid] += v;
        __syncthreads();
    }
    if (tid == 0) off[0] = 0;
    if (tid < 64) { off[tid + 1] = pfx[tid]; woff[tid] = pfx[tid] - cnt[tid]; }
    __syncthreads();
    for (int i = tid; i < c; i += 256) {
        unsigned k = st[i];
        int p = atomicAdd(&woff[k & 63], 1);
        srec[p] = k;
    }
    __syncthreads();

    const uint2* hwq = (const uint2*)hw;   // row = 16 uint2 (64 fp16)
    const int slot = tid >> 4, sub = tid & 15;
    const unsigned no = *ovfn;
    const float4 bb = ((const float4*)bias)[sub];

#define LD1(q) { float2 g01 = __half22float2(*(__half2*)&(q).x); \
                 float2 g23 = __half22float2(*(__half2*)&(q).y); \
                 a0 += g01.x; a1 += g01.y; a2 += g23.x; a3 += g23.y; }

    for (int j = 0; j < 4; j++) {
        int nl = slot * 4 + j;
        int g = b * 64 + nl;
        if (g >= n) break;
        uint2 qs = hwq[(size_t)g * 16 + sub];   // self row
        float a0 = 0.f, a1 = 0.f, a2 = 0.f, a3 = 0.f;
        LD1(qs);

        int e = off[nl], end = off[nl + 1];
        for (; e + 8 <= end; e += 8) {
            uint2 q0 = hwq[(size_t)(srec[e + 0] >> 6) * 16 + sub];
            uint2 q1 = hwq[(size_t)(srec[e + 1] >> 6) * 16 + sub];
            uint2 q2 = hwq[(size_t)(srec[e + 2] >> 6) * 16 + sub];
            uint2 q3 = hwq[(size_t)(srec[e + 3] >> 6) * 16 + sub];
            uint2 q4 = hwq[(size_t)(srec[e + 4] >> 6) * 16 + sub];
            uint2 q5 = hwq[(size_t)(srec[e + 5] >> 6) * 16 + sub];
            uint2 q6 = hwq[(size_t)(srec[e + 6] >> 6) * 16 + sub];
            uint2 q7 = hwq[(size_t)(srec[e + 7] >> 6) * 16 + sub];
            LD1(q0); LD1(q1); LD1(q2); LD1(q3);
            LD1(q4); LD1(q5); LD1(q6); LD1(q7);
        }
        for (; e + 4 <= end; e += 4) {
            uint2 q0 = hwq[(size_t)(srec[e + 0] >> 6) * 16 + sub];
            uint2 q1 = hwq[(size_t)(srec[e + 1] >> 6) * 16 + sub];
            uint2 q2 = hwq[(size_t)(srec[e + 2] >> 6) * 16 + sub];
            uint2 q3 = hwq[(size_t)(srec[e + 3] >> 6) * 16 + sub];
            LD1(q0); LD1(q1); LD1(q2); LD1(q3);
        }
        for (; e < end; e++) {
            uint2 q = hwq[(size_t)(srec[e] >> 6) * 16 + sub];
            LD1(q);
        }
        for (unsigned i = 0; i < no; i++) {
            uint2 o = ovf[i];
            if ((int)o.y == g) { uint2 q = hwq[(size_t)o.x * 16 + sub]; LD1(q); }
        }
        float di = disD[nl];
        float4 oo;
        oo.x = fmaf(di, a0, bb.x);
        oo.y = fmaf(di, a1, bb.y);
        oo.z = fmaf(di, a2, bb.z);
        oo.w = fmaf(di, a3, bb.w);
        oo.x = oo.x > 0.f ? oo.x : 0.f;
        oo.y = oo.y > 0.f ? oo.y : 0.f;
        oo.z = oo.z > 0.f ? oo.z : 0.f;
        oo.w = oo.w > 0.f ? oo.w : 0.f;
        ((float4*)out)[(size_t)g * 16 + sub] = oo;
    }
#undef LD1
}

// ============ MFMA GEMM: C[n,64] = (A[n,K] @ W[K,64]) * dis[row], fp16 out ============
template <int K>
__global__ __launch_bounds__(256) void gemm_mfma(const float* __restrict__ A,
                                                 const float* __restrict__ W,
                                                 const float* __restrict__ dis,
                                                 __half* __restrict__ C, int n) {
    constexpr int KB = K / 32;
    __shared__ f16x8 sAf[4 * KB * 64];   // [rt][kb][lane]
    __shared__ f16x8 sWf[4 * KB * 64];   // [ct][kb][lane]
    __shared__ float sdis[64];
    const int tid = threadIdx.x;
    const int row0 = blockIdx.x * 64;

    if (tid < 64) {
        int rw = row0 + tid;
        sdis[tid] = (rw < n) ? dis[rw] : 0.f;
    }

    _Float16* sAh = (_Float16*)sAf;
    const float4* A4 = (const float4*)A;
#pragma unroll
    for (int it = 0; it < K / 16; ++it) {
        int f = it * 256 + tid;
        int row = f / (K / 4);
        int kq = f % (K / 4);
        int k0 = kq * 4;
        float4 a;
        if (row0 + row < n) a = A4[(size_t)(row0 + row) * (K / 4) + kq];
        else { a.x = 0.f; a.y = 0.f; a.z = 0.f; a.w = 0.f; }
        int rt = row >> 4;
        int kb = k0 >> 5;
        int lane = (row & 15) | (((k0 >> 3) & 3) << 4);
        int base = ((rt * KB + kb) * 64 + lane) * 8 + (k0 & 7);
        sAh[base + 0] = (_Float16)a.x;
        sAh[base + 1] = (_Float16)a.y;
        sAh[base + 2] = (_Float16)a.z;
        sAh[base + 3] = (_Float16)a.w;
    }
    _Float16* sWh = (_Float16*)sWf;
    {
        int nn = tid & 63;
        int ct = nn >> 4;
        int lbase = nn & 15;
        for (int k = tid >> 6; k < K; k += 4) {
            float w = W[(size_t)k * 64 + nn];
            int kb = k >> 5;
            int lane = lbase | (((k >> 3) & 3) << 4);
            sWh[((ct * KB + kb) * 64 + lane) * 8 + (k & 7)] = (_Float16)w;
        }
    }
    __syncthreads();

    const int wv = tid >> 6;
    const int lane = tid & 63;
    f32x4 acc[4];
#pragma unroll
    for (int rt = 0; rt < 4; ++rt) acc[rt] = (f32x4){0.f, 0.f, 0.f, 0.f};

#pragma unroll
    for (int kb = 0; kb < KB; ++kb) {
        f16x8 bf = sWf[(wv * KB + kb) * 64 + lane];
#pragma unroll
        for (int rt = 0; rt < 4; ++rt) {
            f16x8 af = sAf[(rt * KB + kb) * 64 + lane];
            acc[rt] = __builtin_amdgcn_mfma_f32_16x16x32_f16(af, bf, acc[rt], 0, 0, 0);
        }
    }

    int col = wv * 16 + (lane & 15);
    int rbase = (lane >> 4) * 4;
#pragma unroll
    for (int rt = 0; rt < 4; ++rt) {
#pragma unroll
        for (int r = 0; r < 4; ++r) {
            int row = row0 + rt * 16 + rbase + r;
            if (row < n)
                C[(size_t)row * 64 + col] = __float2half(acc[rt][r] * sdis[rt * 16 + rbase + r]);
        }
    }
}

// ================= fallback (atomic path, small ws) =================
__global__ void fill_kernel(float* __restrict__ p, float v, int n) {
    int i = blockIdx.x * blockDim.x + threadIdx.x;
    if (i < n) p[i] = v;
}
__global__ void degree_kernel(const int* __restrict__ ei, float* __restrict__ deg, int E) {
    int stride = gridDim.x * blockDim.x;
    for (int e = blockIdx.x * blockDim.x + threadIdx.x; e < E; e += stride)
        atomicAdd(&deg[ei[E + e]], 1.0f);
}
__global__ void rsqrt_kernel(float* __restrict__ deg, int n) {
    int i = blockIdx.x * blockDim.x + threadIdx.x;
    if (i < n) deg[i] = rsqrtf(deg[i]);
}
template <int K>
__global__ __launch_bounds__(256) void gemm_tile(const float* __restrict__ A,
                                                 const float* __restrict__ W,
                                                 float* __restrict__ C, int n) {
    __shared__ float sA[64 * K];
    __shared__ float sW[K * 64];
    const int tid = threadIdx.x;
    const int row0 = blockIdx.x * 64;
    const int rows = min(64, n - row0);
    const float4* W4 = (const float4*)W;
    float4* sW4 = (float4*)sW;
    for (int i = tid; i < K * 16; i += 256) sW4[i] = W4[i];
    const float4* A4 = (const float4*)(A + (size_t)row0 * K);
    float4* sA4 = (float4*)sA;
    const int nElem = rows * (K / 4);
    for (int i = tid; i < nElem; i += 256) sA4[i] = A4[i];
    __syncthreads();
    const int col = tid & 63;
    const int ty  = tid >> 6;
    float acc[16];
#pragma unroll
    for (int r = 0; r < 16; r++) acc[r] = 0.f;
    for (int k = 0; k < K; k += 4) {
        float w0 = sW[(k + 0) * 64 + col];
        float w1 = sW[(k + 1) * 64 + col];
        float w2 = sW[(k + 2) * 64 + col];
        float w3 = sW[(k + 3) * 64 + col];
#pragma unroll
        for (int r = 0; r < 16; r++) {
            const float4 a = *(const float4*)&sA[(ty + 4 * r) * K + k];
            acc[r] = fmaf(a.x, w0, acc[r]);
            acc[r] = fmaf(a.y, w1, acc[r]);
            acc[r] = fmaf(a.z, w2, acc[r]);
            acc[r] = fmaf(a.w, w3, acc[r]);
        }
    }
#pragma unroll
    for (int r = 0; r < 16; r++) {
        int row = ty + 4 * r;
        if (row < rows) C[(size_t)(row0 + row) * 64 + col] = acc[r];
    }
}
__global__ void scatter_kernel(const int* __restrict__ ei, const float* __restrict__ hw,
                               const float* __restrict__ dis, float* __restrict__ agg, int E) {
    int gtid = blockIdx.x * blockDim.x + threadIdx.x;
    int wave = gtid >> 6, lane = threadIdx.x & 63;
    int nwaves = (gridDim.x * blockDim.x) >> 6;
    for (int e = wave; e < E; e += nwaves) {
        int s = ei[e], d = ei[E + e];
        float v = hw[(size_t)s * 64 + lane] * dis[s] * dis[d];
        atomicAdd(&agg[(size_t)d * 64 + lane], v);
    }
}
__global__ void finalize_kernel(float* __restrict__ agg, const float* __restrict__ hw,
                                const float* __restrict__ dis, const float* __restrict__ b, int n) {
    int i = blockIdx.x * blockDim.x + threadIdx.x;
    if (i < n * 64) {
        int node = i >> 6, col = i & 63;
        float di = dis[node];
        float v = agg[i] + hw[i] * di * di + b[col];
        agg[i] = v > 0.0f ? v : 0.0f;
    }
}

extern "C" void kernel_launch(void* const* d_in, const int* in_sizes, int n_in,
                              void* d_out, int out_size, void* d_ws, size_t ws_size,
                              hipStream_t stream) {
    const float* x  = (const float*)d_in[0];
    const int*   ei = (const int*)d_in[1];   // int32 [2, E] flat
    const float* W1 = (const float*)d_in[2];
    const float* b1 = (const float*)d_in[3];
    const float* W2 = (const float*)d_in[4];
    const float* b2 = (const float*)d_in[5];
    float* out = (float*)d_out;

    const int N = NN, E = NE;
    char* ws = (char*)d_ws;
    const int gemmGrid = (N + 63) / 64;

    if (ws_size >= 38200000u) {
        // ---- factorized-norm bucketed pipeline (hier partition, derived degree) ----
        float*    dis  = (float*)ws;                       // 0 .. 400K (pad 512K)
        int*      cur  = (int*)(ws + (1u << 19));          // 512K (1563 ints)
        unsigned* ovfn = (unsigned*)(ws + 589824u);        // 576K (4B)
        uint2*    ovf  = (uint2*)(ws + 593920u);           // 580K .. +32KB
        unsigned* recs = (unsigned*)(ws + (1u << 20));     // 1M .. 13.8M (NBKT*CAP_B*4)
        __half*   hwa  = (__half*)(ws + 14680064u);        // 14M .. 26.8M (fp16)

        hipMemsetAsync(cur, 0, NBKT * sizeof(int), stream);
        hipMemsetAsync(ovfn, 0, sizeof(unsigned), stream);
        partition_hier<<<PBLK, 256, 0, stream>>>(ei, cur, recs, ovfn, ovf, E);
        bucket_dis<<<NBKT, 256, 0, stream>>>(cur, recs, ovfn, ovf, dis, N);

        // layer 1: hw1(fp16, *dis) -> hwa; h -> out
        gemm_mfma<128><<<gemmGrid, 256, 0, stream>>>(x, W1, dis, hwa, N);
        agg_bucket3<<<NBKT, 256, 0, stream>>>(cur, recs, hwa, dis, b1, out, ovfn, ovf, N);
        // layer 2
        gemm_mfma<64><<<gemmGrid, 256, 0, stream>>>(out, W2, dis, hwa, N);
        agg_bucket3<<<NBKT, 256, 0, stream>>>(cur, recs, hwa, dis, b2, out, ovfn, ovf, N);
    } else {
        // ---- fallback: atomic path (fp32 throughout) ----
        float* dis  = (float*)ws;
        float* bufA = (float*)(ws + (1 << 19));
        const size_t featBytes = (size_t)N * 64 * sizeof(float);

        fill_kernel<<<(N + 255) / 256, 256, 0, stream>>>(dis, 1.0f, N);
        degree_kernel<<<2048, 256, 0, stream>>>(ei, dis, E);
        rsqrt_kernel<<<(N + 255) / 256, 256, 0, stream>>>(dis, N);

        gemm_tile<128><<<gemmGrid, 256, 0, stream>>>(x, W1, bufA, N);
        hipMemsetAsync(out, 0, featBytes, stream);
        scatter_kernel<<<2048, 256, 0, stream>>>(ei, bufA, dis, out, E);
        finalize_kernel<<<(N * 64 + 255) / 256, 256, 0, stream>>>(out, bufA, dis, b1, N);

        gemm_tile<64><<<gemmGrid, 256, 0, stream>>>(out, W2, bufA, N);
        hipMemsetAsync(out, 0, featBytes, stream);
        scatter_kernel<<<2048, 256, 0, stream>>>(ei, bufA, dis, out, E);
        finalize_kernel<<<(N * 64 + 255) / 256, 256, 0, stream>>>(out, bufA, dis, b2, N);
    }
}